// Round 10
// baseline (114.579 us; speedup 1.0000x reference)
//
#include <hip/hip_runtime.h>
#include <hip/hip_bf16.h>
#include <math.h>

// Problem constants: B=32, S=16, D=64, E=768
#define EPSF 1e-12f

typedef short bf16x8 __attribute__((ext_vector_type(8)));
typedef float f32x4  __attribute__((ext_vector_type(4)));

__device__ __forceinline__ float gelu_fast(float x) {
    float x2 = x * x;
    float z = -2.3021184f * x * fmaf(0.044715f, x2, 1.0f);
    float u = __builtin_amdgcn_exp2f(z);
    return x * __builtin_amdgcn_rcpf(1.0f + u);
}
__device__ __forceinline__ float sigmoid_fast(float x) {
    float u = __builtin_amdgcn_exp2f(-1.44269504f * x);
    return __builtin_amdgcn_rcpf(1.0f + u);
}
__device__ __forceinline__ float bf2f(unsigned short u) {
    return __uint_as_float(((unsigned int)u) << 16);
}
__device__ __forceinline__ unsigned short f2bf(float f) {
    unsigned int u = __float_as_uint(f);
    u += 0x7FFFu + ((u >> 16) & 1u);     // RNE
    return (unsigned short)(u >> 16);
}

// ---------------------------------------------------------------------------
// k_prep: [0,640) norms+bf16-cvt; [640,1000) W1/W2 transpose; 1000: copies.
// (unchanged, verified)
// ---------------------------------------------------------------------------
__global__ __launch_bounds__(256) void k_prep(
    const float* __restrict__ doc, const float* __restrict__ seg,
    const float* __restrict__ W1, const float* __restrict__ W2,
    const float* __restrict__ tagg, const float* __restrict__ tis,
    const int* __restrict__ ns,
    float* __restrict__ dscale, float* __restrict__ sscale,
    float* __restrict__ smean, float* __restrict__ cscale,
    unsigned short* __restrict__ docB, unsigned short* __restrict__ segB,
    unsigned short* __restrict__ W1T, unsigned short* __restrict__ W2T,
    float* __restrict__ out)
{
    __shared__ float sT[64][65];
    int blk = blockIdx.x;
    int t = threadIdx.x;
    if (blk == 1000) {
        if (t < 32) out[t] = tagg[t];
        out[32 + t] = tis[t];
        out[32 + 256 + t] = tis[256 + t];
        if (t < 32) out[1056 + t] = (float)ns[t];
        return;
    }
    if (blk < 640) {
        int row = blk * 4 + (t >> 6);
        int lane = t & 63;
        const float* src = (row < 2048) ? (doc + (size_t)row * 768)
                                        : (seg + (size_t)(row - 2048) * 768);
        unsigned short* dst = (row < 2048) ? (docB + (size_t)row * 768)
                                           : (segB + (size_t)(row - 2048) * 768);
        float ss = 0.f, sm = 0.f;
        float xv[12];
        #pragma unroll
        for (int i = 0; i < 12; ++i) {
            float x = src[lane + 64 * i];
            xv[i] = x;
            ss += x * x; sm += x;
        }
        #pragma unroll
        for (int i = 0; i < 12; ++i) dst[lane + 64 * i] = f2bf(xv[i]);
        #pragma unroll
        for (int off = 32; off > 0; off >>= 1) {
            ss += __shfl_down(ss, off);
            sm += __shfl_down(sm, off);
        }
        if (lane == 0) {
            if (row < 2048) {
                dscale[row] = rsqrtf(fmaxf(ss, EPSF));
            } else {
                int r = row - 2048;
                sscale[r] = rsqrtf(fmaxf(ss, EPSF));
                float mean = sm * (1.0f / 768.0f);
                smean[r] = mean;
                cscale[r] = rsqrtf(fmaxf(ss - sm * mean, EPSF));
            }
        }
        return;
    }
    int tt = blk - 640;
    const float* in; unsigned short* out2; int R, C, bx, by;
    if (tt < 288) { in = W1; out2 = W1T; R = 1536; C = 768; bx = tt % 12; by = tt / 12; }
    else { tt -= 288; in = W2; out2 = W2T; R = 768; C = 384; bx = tt % 6; by = tt / 6; }
    int c0 = bx * 64, r0 = by * 64;
    int tr = t >> 2, tc4 = (t & 3) * 16;
    #pragma unroll
    for (int i = 0; i < 4; ++i) {
        float4 v = *(const float4*)(in + (size_t)(r0 + tr) * C + c0 + tc4 + i * 4);
        sT[tr][tc4 + i * 4 + 0] = v.x; sT[tr][tc4 + i * 4 + 1] = v.y;
        sT[tr][tc4 + i * 4 + 2] = v.z; sT[tr][tc4 + i * 4 + 3] = v.w;
    }
    __syncthreads();
    union { uint4 v; unsigned short u[8]; } o0, o1;
    #pragma unroll
    for (int i = 0; i < 8; ++i) o0.u[i] = f2bf(sT[tc4 + i][tr]);
    #pragma unroll
    for (int i = 0; i < 8; ++i) o1.u[i] = f2bf(sT[tc4 + 8 + i][tr]);
    *(uint4*)(out2 + (size_t)(c0 + tr) * R + r0 + tc4) = o0.v;
    *(uint4*)(out2 + (size_t)(c0 + tr) * R + r0 + tc4 + 8) = o1.v;
}

// ---------------------------------------------------------------------------
// Layer-1 MFMA GEMM (unchanged, verified round 6).
// ---------------------------------------------------------------------------
__global__ __launch_bounds__(256) void k_l1(
    const unsigned short* __restrict__ docB, const unsigned short* __restrict__ segB,
    const unsigned short* __restrict__ W1T_bf, const float* __restrict__ b1,
    unsigned short* __restrict__ XdocB, unsigned short* __restrict__ XsegB)
{
    int mb = blockIdx.x;
    int n0 = blockIdx.y * 128;
    int t = threadIdx.x, w = t >> 6, l = t & 63;
    int lm = l & 15, kh = l >> 4;
    bool isdoc = (mb < 32);
    int m0 = isdoc ? mb * 64 : (mb - 32) * 64;
    const unsigned short* A = isdoc ? docB : segB;
    int koff = isdoc ? 0 : 768;
    unsigned short* C = isdoc ? XdocB : XsegB;

    const unsigned short* gA = A + (size_t)(m0 + lm) * 768 + kh * 8;
    const unsigned short* gB = W1T_bf + (size_t)(n0 + w * 32 + lm) * 1536 + koff + kh * 8;

    f32x4 acc[4][2];
    #pragma unroll
    for (int mt = 0; mt < 4; ++mt)
        #pragma unroll
        for (int nt = 0; nt < 2; ++nt) acc[mt][nt] = (f32x4){0.f, 0.f, 0.f, 0.f};

    bf16x8 aA[4], aB[4], bA[2], bB[2];
    #pragma unroll
    for (int mt = 0; mt < 4; ++mt) aA[mt] = *(const bf16x8*)(gA + (size_t)mt * 16 * 768);
    #pragma unroll
    for (int nt = 0; nt < 2; ++nt) bA[nt] = *(const bf16x8*)(gB + (size_t)nt * 16 * 1536);

    for (int kt = 0; kt < 12; ++kt) {
        int ko1 = kt * 64 + 32;
        #pragma unroll
        for (int mt = 0; mt < 4; ++mt) aB[mt] = *(const bf16x8*)(gA + (size_t)mt * 16 * 768 + ko1);
        #pragma unroll
        for (int nt = 0; nt < 2; ++nt) bB[nt] = *(const bf16x8*)(gB + (size_t)nt * 16 * 1536 + ko1);
        #pragma unroll
        for (int mt = 0; mt < 4; ++mt)
            #pragma unroll
            for (int nt = 0; nt < 2; ++nt)
                acc[mt][nt] = __builtin_amdgcn_mfma_f32_16x16x32_bf16(
                    aA[mt], bA[nt], acc[mt][nt], 0, 0, 0);
        if (kt < 11) {
            int ko2 = kt * 64 + 64;
            #pragma unroll
            for (int mt = 0; mt < 4; ++mt) aA[mt] = *(const bf16x8*)(gA + (size_t)mt * 16 * 768 + ko2);
            #pragma unroll
            for (int nt = 0; nt < 2; ++nt) bA[nt] = *(const bf16x8*)(gB + (size_t)nt * 16 * 1536 + ko2);
        }
        #pragma unroll
        for (int mt = 0; mt < 4; ++mt)
            #pragma unroll
            for (int nt = 0; nt < 2; ++nt)
                acc[mt][nt] = __builtin_amdgcn_mfma_f32_16x16x32_bf16(
                    aB[mt], bB[nt], acc[mt][nt], 0, 0, 0);
    }
    #pragma unroll
    for (int nt = 0; nt < 2; ++nt) {
        int n = n0 + w * 32 + nt * 16 + lm;
        float bv = isdoc ? 0.f : b1[n];
        #pragma unroll
        for (int mt = 0; mt < 4; ++mt)
            #pragma unroll
            for (int j = 0; j < 4; ++j) {
                int row = m0 + mt * 16 + kh * 4 + j;
                C[(size_t)row * 768 + n] = f2bf(acc[mt][nt][j] + bv);
            }
    }
}

// ---------------------------------------------------------------------------
// Fused layer-2+3: 256 threads, barrier-free K-loop, M=32 half-tiles.
// blocks [0,32): cos rider; [32,64): corr rider; [64,1088): pred.
// Pred: XCD-chunked swizzle; stage 32x768 h1-half (48KB swizzled LDS) ->
// ONE barrier -> MFMA loop (2 m-tiles x 6 n-tiles/wave) with 1-deep B-reg
// prefetch from L2, zero barriers -> partial d-max to predhalf.
// ---------------------------------------------------------------------------
__global__ __launch_bounds__(256, 3) void k_fused_mfma(
    const unsigned short* __restrict__ XdocB, const unsigned short* __restrict__ XsegB,
    const unsigned short* __restrict__ W2T_bf,
    const float* __restrict__ b2, const float* __restrict__ W3, const float* __restrict__ b3,
    const int* __restrict__ nd,
    const unsigned short* __restrict__ docB, const unsigned short* __restrict__ segB,
    const float* __restrict__ seg,
    const float* __restrict__ dscale, const float* __restrict__ sscale,
    const float* __restrict__ smean, const float* __restrict__ cscale,
    float* __restrict__ predhalf, float* __restrict__ dcws, float* __restrict__ Rws)
{
    __shared__ union {
        struct {
            unsigned short sH1[32 * 768];   // 48KB, swizzled rows of 1536B
            float sRed[32][4];
        } p;
        struct { float sRedC[16][4]; } c;
        struct { unsigned short zb[16][776]; } r;   // ~24.8KB
    } U;

    int blk = blockIdx.x;
    int t = threadIdx.x, w = t >> 6, l = t & 63;
    int lm = l & 15, kh = l >> 4;
    union u128 { uint4 v; unsigned short u[8]; };

    if (blk < 32) {
        // ---- cos rider ----
        int b = blk;
        const unsigned short* gS = segB + (size_t)(b * 16 + lm) * 768 + kh * 8;
        const unsigned short* gD = docB + (size_t)(b * 64 + w * 16 + lm) * 768 + kh * 8;
        f32x4 acc = (f32x4){0.f, 0.f, 0.f, 0.f};
        for (int kt = 0; kt < 24; ++kt) {
            bf16x8 a = *(const bf16x8*)(gS + kt * 32);
            bf16x8 bb = *(const bf16x8*)(gD + kt * 32);
            acc = __builtin_amdgcn_mfma_f32_16x16x32_bf16(a, bb, acc, 0, 0, 0);
        }
        int ndb = nd[b];
        int d = w * 16 + lm;
        float dsc = dscale[b * 64 + d];
        #pragma unroll
        for (int j = 0; j < 4; ++j) {
            int s = kh * 4 + j;
            float cosv = acc[j] * sscale[b * 16 + s] * dsc;
            float sim = (d < ndb) ? (1.0f - cosv) * 0.5f : 0.f;
            sim = fmaxf(sim, __shfl_xor(sim, 1));
            sim = fmaxf(sim, __shfl_xor(sim, 2));
            sim = fmaxf(sim, __shfl_xor(sim, 4));
            sim = fmaxf(sim, __shfl_xor(sim, 8));
            if (lm == 0) U.c.sRedC[s][w] = sim;
        }
        __syncthreads();
        if (t < 16) {
            float dc = fmaxf(fmaxf(U.c.sRedC[t][0], U.c.sRedC[t][1]),
                             fmaxf(U.c.sRedC[t][2], U.c.sRedC[t][3]));
            dcws[b * 16 + t] = dc;
        }
        return;
    }
    if (blk < 64) {
        // ---- corr rider: R = (1 + z.z^T)/2 via MFMA ----
        int b = blk - 32;
        for (int i = t; i < 16 * 768; i += 256) {
            int s = i / 768; int e = i - s * 768;
            U.r.zb[s][e] = f2bf((seg[((size_t)b * 16 + s) * 768 + e]
                                 - smean[b * 16 + s]) * cscale[b * 16 + s]);
        }
        __syncthreads();
        if (w == 0) {
            f32x4 acc = (f32x4){0.f, 0.f, 0.f, 0.f};
            #pragma unroll
            for (int kt = 0; kt < 24; ++kt) {
                bf16x8 z = *(const bf16x8*)&U.r.zb[lm][kt * 32 + kh * 8];
                acc = __builtin_amdgcn_mfma_f32_16x16x32_bf16(z, z, acc, 0, 0, 0);
            }
            #pragma unroll
            for (int j = 0; j < 4; ++j) {
                int row = kh * 4 + j;
                Rws[b * 256 + row * 16 + lm] = 0.5f * (1.0f + acc[j]);
            }
        }
        return;
    }

    // ---------------- pred path ----------------
    // XCD-chunked swizzle: same-b blocks land on one XCD (m09/m157).
    int p = blk - 64;                       // 0..1023
    int lidx = (p & 7) * 128 + (p >> 3);    // bijective (1024 % 8 == 0)
    int half = lidx & 1;
    int bs = lidx >> 1;
    int b = bs >> 4;
    const int ndb = nd[b];

    // stage h1-half: 32 rows x 768 cols, gelu(Xdoc+Xseg), swizzled
    {
        int r = t >> 3, ci = t & 7;
        int rsw = (r & 7) << 4;
        const unsigned short* gXd = XdocB + (size_t)(b * 64 + half * 32 + r) * 768;
        const unsigned short* gXs = XsegB + (size_t)bs * 768;
        #pragma unroll
        for (int i = 0; i < 12; ++i) {
            int c = i * 8 + ci;
            int k0 = c * 8;
            u128 xd, xs, o;
            xd.v = *(const uint4*)(gXd + k0);
            xs.v = *(const uint4*)(gXs + k0);
            #pragma unroll
            for (int j = 0; j < 8; ++j)
                o.u[j] = f2bf(gelu_fast(bf2f(xd.u[j]) + bf2f(xs.u[j])));
            *(uint4*)((char*)U.p.sH1 + r * 1536 + ((c * 16) ^ rsw)) = o.v;
        }
    }
    __syncthreads();   // the ONLY barrier before epilogue

    // barrier-free MFMA loop: wave w owns n-cols [w*96, w*96+96)
    f32x4 acc[2][6];
    #pragma unroll
    for (int mt = 0; mt < 2; ++mt)
        #pragma unroll
        for (int nt = 0; nt < 6; ++nt) acc[mt][nt] = (f32x4){0.f, 0.f, 0.f, 0.f};

    const unsigned short* gW2w = W2T_bf + (size_t)(w * 96 + lm) * 768 + kh * 8;
    int asw = (lm & 7) << 4;

    bf16x8 bbA[6], bbB[6];
    #pragma unroll
    for (int nt = 0; nt < 6; ++nt)
        bbA[nt] = *(const bf16x8*)(gW2w + (size_t)nt * 16 * 768);

    #pragma unroll
    for (int kt = 0; kt < 12; ++kt) {
        // kk = 0: prefetch bbB (this kt's kk=1), compute with bbA
        {
            #pragma unroll
            for (int nt = 0; nt < 6; ++nt)
                bbB[nt] = *(const bf16x8*)(gW2w + (size_t)nt * 16 * 768 + kt * 64 + 32);
            int koff = kt * 128 + kh * 16;
            bf16x8 a_[2];
            #pragma unroll
            for (int mt = 0; mt < 2; ++mt)
                a_[mt] = *(const bf16x8*)((const char*)U.p.sH1
                            + (mt * 16 + lm) * 1536 + (koff ^ asw));
            #pragma unroll
            for (int mt = 0; mt < 2; ++mt)
                #pragma unroll
                for (int nt = 0; nt < 6; ++nt)
                    acc[mt][nt] = __builtin_amdgcn_mfma_f32_16x16x32_bf16(
                        a_[mt], bbA[nt], acc[mt][nt], 0, 0, 0);
        }
        // kk = 1: prefetch bbA (next kt's kk=0), compute with bbB
        {
            if (kt < 11) {
                #pragma unroll
                for (int nt = 0; nt < 6; ++nt)
                    bbA[nt] = *(const bf16x8*)(gW2w + (size_t)nt * 16 * 768 + (kt + 1) * 64);
            }
            int koff = kt * 128 + 64 + kh * 16;
            bf16x8 a_[2];
            #pragma unroll
            for (int mt = 0; mt < 2; ++mt)
                a_[mt] = *(const bf16x8*)((const char*)U.p.sH1
                            + (mt * 16 + lm) * 1536 + (koff ^ asw));
            #pragma unroll
            for (int mt = 0; mt < 2; ++mt)
                #pragma unroll
                for (int nt = 0; nt < 6; ++nt)
                    acc[mt][nt] = __builtin_amdgcn_mfma_f32_16x16x32_bf16(
                        a_[mt], bbB[nt], acc[mt][nt], 0, 0, 0);
        }
    }

    // epilogue: h3 = sum_n gelu(h2+b2)*W3; sigmoid; masked partial max
    float b2v[6], w3v[6];
    #pragma unroll
    for (int nt = 0; nt < 6; ++nt) {
        int n = w * 96 + nt * 16 + lm;
        b2v[nt] = b2[n]; w3v[nt] = W3[n];
    }
    #pragma unroll
    for (int mt = 0; mt < 2; ++mt) {
        #pragma unroll
        for (int j = 0; j < 4; ++j) {
            float s = 0.f;
            #pragma unroll
            for (int nt = 0; nt < 6; ++nt)
                s += gelu_fast(acc[mt][nt][j] + b2v[nt]) * w3v[nt];
            s += __shfl_xor(s, 1); s += __shfl_xor(s, 2);
            s += __shfl_xor(s, 4); s += __shfl_xor(s, 8);
            if (lm == 0) U.p.sRed[mt * 16 + kh * 4 + j][w] = s;
        }
    }
    __syncthreads();
    if (w == 0) {
        float val = 0.f;
        if (l < 32) {
            float h3 = U.p.sRed[l][0] + U.p.sRed[l][1] + U.p.sRed[l][2]
                     + U.p.sRed[l][3] + b3[0];
            float sig = sigmoid_fast(h3);
            int d = half * 32 + l;
            val = (d < ndb) ? sig : 0.f;
        }
        #pragma unroll
        for (int off = 16; off > 0; off >>= 1) val = fmaxf(val, __shfl_xor(val, off));
        if (l == 0) predhalf[half * 512 + bs] = val;
    }
}

// ---------------------------------------------------------------------------
// k_final: finalize pred from halves (+ write out_pred), cos & corr priors.
// ---------------------------------------------------------------------------
__global__ __launch_bounds__(256) void k_final(
    const int* __restrict__ ns, const float* __restrict__ dcws,
    const float* __restrict__ Rws, const float* __restrict__ predhalf,
    float* __restrict__ out)
{
    __shared__ float sP[512];
    __shared__ float sl1[32], sl2[32];
    int t = threadIdx.x;
    for (int i = t; i < 512; i += 256) {
        int b = i >> 4;
        float scale = (ns[b] > 10) ? 1.0f : 100.0f;
        float pv = scale * fmaxf(predhalf[i], predhalf[512 + i]);
        sP[i] = pv;
        out[544 + i] = pv;
    }
    __syncthreads();
    if (t < 32) {
        int nsb = ns[t];
        float sb = 0.f;
        #pragma unroll
        for (int s = 0; s < 16; ++s) {
            float d = fabsf(dcws[t * 16 + s] - sP[t * 16 + s]);
            sb += (s < nsb) ? d : 0.f;
        }
        sl1[t] = sb / (float)nsb;
    }
    {
        int b = t >> 3, c = t & 7;
        int nsb = ns[b];
        float sum = 0.f;
        #pragma unroll
        for (int k = 0; k < 32; ++k) {
            int idx = c * 32 + k;
            int s = idx >> 4, tt = idx & 15;
            float R = Rws[b * 256 + idx];
            float ps = sP[b * 16 + s], pt = sP[b * 16 + tt];
            float t1 = (1.f - ps) * (1.f - pt), t2 = ps * pt;
            float term = fabsf(t1 - R) * fabsf(t2 - R);
            sum += (s < nsb && tt < nsb) ? term : 0.f;
        }
        sum += __shfl_xor(sum, 1);
        sum += __shfl_xor(sum, 2);
        sum += __shfl_xor(sum, 4);
        if (c == 0) sl2[b] = sum / (float)nsb;
    }
    __syncthreads();
    if (t == 0) {
        float a = 0.f, bsum = 0.f;
        #pragma unroll
        for (int i = 0; i < 32; ++i) { a += sl1[i]; bsum += sl2[i]; }
        out[1088] = a * (1.0f / 32.0f);
        out[1089] = bsum * (1.0f / 32.0f);
    }
}

// ---------------------------------------------------------------------------
extern "C" void kernel_launch(void* const* d_in, const int* in_sizes, int n_in,
                              void* d_out, int out_size, void* d_ws, size_t ws_size,
                              hipStream_t stream)
{
    const float* doc  = (const float*)d_in[0];
    const float* seg  = (const float*)d_in[1];
    const int*   nd   = (const int*)d_in[2];
    const int*   ns   = (const int*)d_in[3];
    const float* tagg = (const float*)d_in[4];
    const float* tis  = (const float*)d_in[5];
    const float* W1   = (const float*)d_in[6];   // [1536][768]
    const float* b1   = (const float*)d_in[7];
    const float* W2   = (const float*)d_in[8];   // [768][384]
    const float* b2   = (const float*)d_in[9];
    const float* W3   = (const float*)d_in[10];
    const float* b3   = (const float*)d_in[11];
    float* out = (float*)d_out;

    float* fws      = (float*)d_ws;
    float* dscale   = fws;                 // 2048
    float* sscale   = dscale + 2048;       // 512
    float* smean    = sscale + 512;        // 512
    float* cscale   = smean + 512;         // 512
    float* predhalf = cscale + 512;        // 1024
    float* dcws     = predhalf + 1024;     // 512
    float* Rws      = dcws + 512;          // 8192
    unsigned short* docB  = (unsigned short*)(Rws + 8192);
    unsigned short* segB  = docB + (size_t)2048 * 768;
    unsigned short* W1T   = segB + (size_t)512 * 768;     // [768][1536]
    unsigned short* W2T   = W1T + (size_t)768 * 1536;     // [384][768]
    unsigned short* XdocB = W2T + (size_t)384 * 768;      // [2048][768]
    unsigned short* XsegB = XdocB + (size_t)2048 * 768;   // [512][768]

    k_prep<<<1001, 256, 0, stream>>>(doc, seg, W1, W2, tagg, tis, ns,
                                     dscale, sscale, smean, cscale,
                                     docB, segB, W1T, W2T, out);
    k_l1<<<dim3(40, 6), 256, 0, stream>>>(docB, segB, W1T, b1, XdocB, XsegB);
    k_fused_mfma<<<1088, 256, 0, stream>>>(XdocB, XsegB, W2T, b2, W3, b3, nd,
                                           docB, segB, seg, dscale, sscale,
                                           smean, cscale, predhalf, dcws, Rws);
    k_final<<<1, 256, 0, stream>>>(ns, dcws, Rws, predhalf, out);
}

// Round 11
// 87.691 us; speedup vs baseline: 1.3066x; 1.3066x over previous
//
#include <hip/hip_runtime.h>
#include <hip/hip_bf16.h>
#include <math.h>

// Problem constants: B=32, S=16, D=64, E=768
#define EPSF 1e-12f

typedef short bf16x8 __attribute__((ext_vector_type(8)));
typedef float f32x4  __attribute__((ext_vector_type(4)));

__device__ __forceinline__ float gelu_fast(float x) {
    float x2 = x * x;
    float z = -2.3021184f * x * fmaf(0.044715f, x2, 1.0f);
    float u = __builtin_amdgcn_exp2f(z);
    return x * __builtin_amdgcn_rcpf(1.0f + u);
}
__device__ __forceinline__ float sigmoid_fast(float x) {
    float u = __builtin_amdgcn_exp2f(-1.44269504f * x);
    return __builtin_amdgcn_rcpf(1.0f + u);
}
__device__ __forceinline__ float bf2f(unsigned short u) {
    return __uint_as_float(((unsigned int)u) << 16);
}
__device__ __forceinline__ unsigned short f2bf(float f) {
    unsigned int u = __float_as_uint(f);
    u += 0x7FFFu + ((u >> 16) & 1u);     // RNE
    return (unsigned short)(u >> 16);
}

// ---------------------------------------------------------------------------
// k_prep: [0,640) norms+bf16-cvt; [640,1000) W1/W2 transpose; 1000: copies.
// (unchanged, verified)
// ---------------------------------------------------------------------------
__global__ __launch_bounds__(256) void k_prep(
    const float* __restrict__ doc, const float* __restrict__ seg,
    const float* __restrict__ W1, const float* __restrict__ W2,
    const float* __restrict__ tagg, const float* __restrict__ tis,
    const int* __restrict__ ns,
    float* __restrict__ dscale, float* __restrict__ sscale,
    float* __restrict__ smean, float* __restrict__ cscale,
    unsigned short* __restrict__ docB, unsigned short* __restrict__ segB,
    unsigned short* __restrict__ W1T, unsigned short* __restrict__ W2T,
    float* __restrict__ out)
{
    __shared__ float sT[64][65];
    int blk = blockIdx.x;
    int t = threadIdx.x;
    if (blk == 1000) {
        if (t < 32) out[t] = tagg[t];
        out[32 + t] = tis[t];
        out[32 + 256 + t] = tis[256 + t];
        if (t < 32) out[1056 + t] = (float)ns[t];
        return;
    }
    if (blk < 640) {
        int row = blk * 4 + (t >> 6);
        int lane = t & 63;
        const float* src = (row < 2048) ? (doc + (size_t)row * 768)
                                        : (seg + (size_t)(row - 2048) * 768);
        unsigned short* dst = (row < 2048) ? (docB + (size_t)row * 768)
                                           : (segB + (size_t)(row - 2048) * 768);
        float ss = 0.f, sm = 0.f;
        float xv[12];
        #pragma unroll
        for (int i = 0; i < 12; ++i) {
            float x = src[lane + 64 * i];
            xv[i] = x;
            ss += x * x; sm += x;
        }
        #pragma unroll
        for (int i = 0; i < 12; ++i) dst[lane + 64 * i] = f2bf(xv[i]);
        #pragma unroll
        for (int off = 32; off > 0; off >>= 1) {
            ss += __shfl_down(ss, off);
            sm += __shfl_down(sm, off);
        }
        if (lane == 0) {
            if (row < 2048) {
                dscale[row] = rsqrtf(fmaxf(ss, EPSF));
            } else {
                int r = row - 2048;
                sscale[r] = rsqrtf(fmaxf(ss, EPSF));
                float mean = sm * (1.0f / 768.0f);
                smean[r] = mean;
                cscale[r] = rsqrtf(fmaxf(ss - sm * mean, EPSF));
            }
        }
        return;
    }
    int tt = blk - 640;
    const float* in; unsigned short* out2; int R, C, bx, by;
    if (tt < 288) { in = W1; out2 = W1T; R = 1536; C = 768; bx = tt % 12; by = tt / 12; }
    else { tt -= 288; in = W2; out2 = W2T; R = 768; C = 384; bx = tt % 6; by = tt / 6; }
    int c0 = bx * 64, r0 = by * 64;
    int tr = t >> 2, tc4 = (t & 3) * 16;
    #pragma unroll
    for (int i = 0; i < 4; ++i) {
        float4 v = *(const float4*)(in + (size_t)(r0 + tr) * C + c0 + tc4 + i * 4);
        sT[tr][tc4 + i * 4 + 0] = v.x; sT[tr][tc4 + i * 4 + 1] = v.y;
        sT[tr][tc4 + i * 4 + 2] = v.z; sT[tr][tc4 + i * 4 + 3] = v.w;
    }
    __syncthreads();
    union { uint4 v; unsigned short u[8]; } o0, o1;
    #pragma unroll
    for (int i = 0; i < 8; ++i) o0.u[i] = f2bf(sT[tc4 + i][tr]);
    #pragma unroll
    for (int i = 0; i < 8; ++i) o1.u[i] = f2bf(sT[tc4 + 8 + i][tr]);
    *(uint4*)(out2 + (size_t)(c0 + tr) * R + r0 + tc4) = o0.v;
    *(uint4*)(out2 + (size_t)(c0 + tr) * R + r0 + tc4 + 8) = o1.v;
}

// ---------------------------------------------------------------------------
// Layer-1 MFMA GEMM (unchanged, verified round 6).
// ---------------------------------------------------------------------------
__global__ __launch_bounds__(256) void k_l1(
    const unsigned short* __restrict__ docB, const unsigned short* __restrict__ segB,
    const unsigned short* __restrict__ W1T_bf, const float* __restrict__ b1,
    unsigned short* __restrict__ XdocB, unsigned short* __restrict__ XsegB)
{
    int mb = blockIdx.x;
    int n0 = blockIdx.y * 128;
    int t = threadIdx.x, w = t >> 6, l = t & 63;
    int lm = l & 15, kh = l >> 4;
    bool isdoc = (mb < 32);
    int m0 = isdoc ? mb * 64 : (mb - 32) * 64;
    const unsigned short* A = isdoc ? docB : segB;
    int koff = isdoc ? 0 : 768;
    unsigned short* C = isdoc ? XdocB : XsegB;

    const unsigned short* gA = A + (size_t)(m0 + lm) * 768 + kh * 8;
    const unsigned short* gB = W1T_bf + (size_t)(n0 + w * 32 + lm) * 1536 + koff + kh * 8;

    f32x4 acc[4][2];
    #pragma unroll
    for (int mt = 0; mt < 4; ++mt)
        #pragma unroll
        for (int nt = 0; nt < 2; ++nt) acc[mt][nt] = (f32x4){0.f, 0.f, 0.f, 0.f};

    bf16x8 aA[4], aB[4], bA[2], bB[2];
    #pragma unroll
    for (int mt = 0; mt < 4; ++mt) aA[mt] = *(const bf16x8*)(gA + (size_t)mt * 16 * 768);
    #pragma unroll
    for (int nt = 0; nt < 2; ++nt) bA[nt] = *(const bf16x8*)(gB + (size_t)nt * 16 * 1536);

    for (int kt = 0; kt < 12; ++kt) {
        int ko1 = kt * 64 + 32;
        #pragma unroll
        for (int mt = 0; mt < 4; ++mt) aB[mt] = *(const bf16x8*)(gA + (size_t)mt * 16 * 768 + ko1);
        #pragma unroll
        for (int nt = 0; nt < 2; ++nt) bB[nt] = *(const bf16x8*)(gB + (size_t)nt * 16 * 1536 + ko1);
        #pragma unroll
        for (int mt = 0; mt < 4; ++mt)
            #pragma unroll
            for (int nt = 0; nt < 2; ++nt)
                acc[mt][nt] = __builtin_amdgcn_mfma_f32_16x16x32_bf16(
                    aA[mt], bA[nt], acc[mt][nt], 0, 0, 0);
        if (kt < 11) {
            int ko2 = kt * 64 + 64;
            #pragma unroll
            for (int mt = 0; mt < 4; ++mt) aA[mt] = *(const bf16x8*)(gA + (size_t)mt * 16 * 768 + ko2);
            #pragma unroll
            for (int nt = 0; nt < 2; ++nt) bA[nt] = *(const bf16x8*)(gB + (size_t)nt * 16 * 1536 + ko2);
        }
        #pragma unroll
        for (int mt = 0; mt < 4; ++mt)
            #pragma unroll
            for (int nt = 0; nt < 2; ++nt)
                acc[mt][nt] = __builtin_amdgcn_mfma_f32_16x16x32_bf16(
                    aB[mt], bB[nt], acc[mt][nt], 0, 0, 0);
    }
    #pragma unroll
    for (int nt = 0; nt < 2; ++nt) {
        int n = n0 + w * 32 + nt * 16 + lm;
        float bv = isdoc ? 0.f : b1[n];
        #pragma unroll
        for (int mt = 0; mt < 4; ++mt)
            #pragma unroll
            for (int j = 0; j < 4; ++j) {
                int row = m0 + mt * 16 + kh * 4 + j;
                C[(size_t)row * 768 + n] = f2bf(acc[mt][nt][j] + bv);
            }
    }
}

// ---------------------------------------------------------------------------
// Fused layer-2+3: 512 threads (8 waves), r6-verified per-kt structure.
// blocks [0,32): cos rider; [32,64): corr rider; [64,576): pred (bs=blk-64).
// Pred: M=64, each wave owns 48 n-cols (3 nt). LDS 64x64 dbuf tiles (128B
// rows, conflict-free layout from r6), 1-deep B-register prefetch,
// issue-early/write-late staging. 2 blocks/CU -> 4 waves/SIMD.
// ---------------------------------------------------------------------------
__global__ __launch_bounds__(512, 4) void k_fused_mfma(
    const unsigned short* __restrict__ XdocB, const unsigned short* __restrict__ XsegB,
    const unsigned short* __restrict__ W2T_bf,
    const float* __restrict__ b2, const float* __restrict__ W3, const float* __restrict__ b3,
    const int* __restrict__ nd, const int* __restrict__ ns,
    const unsigned short* __restrict__ docB, const unsigned short* __restrict__ segB,
    const float* __restrict__ seg,
    const float* __restrict__ dscale, const float* __restrict__ sscale,
    const float* __restrict__ smean, const float* __restrict__ cscale,
    float* __restrict__ out_pred, float* __restrict__ predv,
    float* __restrict__ dcws, float* __restrict__ Rws)
{
    __shared__ union {
        struct {
            unsigned short sA0[64 * 64];   // 8KB, swizzled rows of 128B
            unsigned short sA1[64 * 64];   // 8KB
            float sXseg[768];              // 3KB
            float sRed[64][8];             // 2KB
        } p;
        struct { float sRedC[16][4]; } c;
        struct { unsigned short zb[16][776]; } r;   // ~24.8KB
    } U;

    int blk = blockIdx.x;
    int t = threadIdx.x, w = t >> 6, l = t & 63;
    int lm = l & 15, kh = l >> 4;
    union u128 { uint4 v; unsigned short u[8]; };

    if (blk < 32) {
        // ---- cos rider: waves 0-3 compute, 4-7 barrier-only ----
        int b = blk;
        if (w < 4) {
            const unsigned short* gS = segB + (size_t)(b * 16 + lm) * 768 + kh * 8;
            const unsigned short* gD = docB + (size_t)(b * 64 + w * 16 + lm) * 768 + kh * 8;
            f32x4 acc = (f32x4){0.f, 0.f, 0.f, 0.f};
            for (int kt = 0; kt < 24; ++kt) {
                bf16x8 a = *(const bf16x8*)(gS + kt * 32);
                bf16x8 bb = *(const bf16x8*)(gD + kt * 32);
                acc = __builtin_amdgcn_mfma_f32_16x16x32_bf16(a, bb, acc, 0, 0, 0);
            }
            int ndb = nd[b];
            int d = w * 16 + lm;
            float dsc = dscale[b * 64 + d];
            #pragma unroll
            for (int j = 0; j < 4; ++j) {
                int s = kh * 4 + j;
                float cosv = acc[j] * sscale[b * 16 + s] * dsc;
                float sim = (d < ndb) ? (1.0f - cosv) * 0.5f : 0.f;
                sim = fmaxf(sim, __shfl_xor(sim, 1));
                sim = fmaxf(sim, __shfl_xor(sim, 2));
                sim = fmaxf(sim, __shfl_xor(sim, 4));
                sim = fmaxf(sim, __shfl_xor(sim, 8));
                if (lm == 0) U.c.sRedC[s][w] = sim;
            }
        }
        __syncthreads();
        if (t < 16) {
            float dc = fmaxf(fmaxf(U.c.sRedC[t][0], U.c.sRedC[t][1]),
                             fmaxf(U.c.sRedC[t][2], U.c.sRedC[t][3]));
            dcws[blk * 16 + t] = dc;
        }
        return;
    }
    if (blk < 64) {
        // ---- corr rider: R = (1 + z.z^T)/2 via MFMA ----
        int b = blk - 32;
        for (int i = t; i < 16 * 768; i += 512) {
            int s = i / 768; int e = i - s * 768;
            U.r.zb[s][e] = f2bf((seg[((size_t)b * 16 + s) * 768 + e]
                                 - smean[b * 16 + s]) * cscale[b * 16 + s]);
        }
        __syncthreads();
        if (w == 0) {
            f32x4 acc = (f32x4){0.f, 0.f, 0.f, 0.f};
            #pragma unroll
            for (int kt = 0; kt < 24; ++kt) {
                bf16x8 z = *(const bf16x8*)&U.r.zb[lm][kt * 32 + kh * 8];
                acc = __builtin_amdgcn_mfma_f32_16x16x32_bf16(z, z, acc, 0, 0, 0);
            }
            #pragma unroll
            for (int j = 0; j < 4; ++j) {
                int row = kh * 4 + j;
                Rws[b * 256 + row * 16 + lm] = 0.5f * (1.0f + acc[j]);
            }
        }
        return;
    }

    // ---------------- pred path ----------------
    int bs = blk - 64;
    int b = bs >> 4;
    int sw2 = (lm & 7) << 4;

    for (int i = t; i < 768; i += 512) U.p.sXseg[i] = bf2f(XsegB[(size_t)bs * 768 + i]);

    const int ndb = nd[b];
    const float segscale = (ns[b] > 10) ? 1.0f : 100.0f;
    const float b3v = b3[0];

    f32x4 acc[4][3];
    #pragma unroll
    for (int mt = 0; mt < 4; ++mt)
        #pragma unroll
        for (int nt = 0; nt < 3; ++nt) acc[mt][nt] = (f32x4){0.f, 0.f, 0.f, 0.f};

    // staging: 512 threads, thread t -> row ar = t>>3, 8 elems at ci*8
    int ar = t >> 3, ci = t & 7;
    int asw = (ar & 7) << 4;
    const char* gXd = (const char*)XdocB + (size_t)(b * 64 + ar) * 1536;
    const unsigned short* gW2w = W2T_bf + (size_t)(w * 48 + lm) * 768 + kh * 8;

    // B register double-buffer: bbA = next kk=0 fragments; bbB = next kk=1.
    bf16x8 bbA[3], bbB[3];
    #pragma unroll
    for (int nt = 0; nt < 3; ++nt)
        bbA[nt] = *(const bf16x8*)(gW2w + (size_t)nt * 16 * 768);

    // prologue: load + gelu + write kt=0 into sA0
    {
        u128 xc;
        xc.v = *(const uint4*)(gXd + ci * 16);
        __syncthreads();          // sXseg ready
        u128 o;
        #pragma unroll
        for (int i = 0; i < 8; ++i)
            o.u[i] = f2bf(gelu_fast(bf2f(xc.u[i]) + U.p.sXseg[ci * 8 + i]));
        *(uint4*)((char*)U.p.sA0 + ar * 128 + ((ci * 16) ^ asw)) = o.v;
    }

    #pragma unroll
    for (int kt = 0; kt < 12; ++kt) {
        unsigned short* cbuf = (kt & 1) ? U.p.sA1 : U.p.sA0;
        unsigned short* nbuf = (kt & 1) ? U.p.sA0 : U.p.sA1;
        __syncthreads();      // cbuf writes visible; prior nbuf reads done
        // issue-early: next K-chunk's Xdoc load
        u128 xn;
        if (kt < 11) xn.v = *(const uint4*)(gXd + (kt + 1) * 128 + ci * 16);
        // ---- kk = 0: prefetch bbB (this kt's kk=1), compute with bbA ----
        {
            #pragma unroll
            for (int nt = 0; nt < 3; ++nt)
                bbB[nt] = *(const bf16x8*)(gW2w + (size_t)nt * 16 * 768 + kt * 64 + 32);
            int kb = (kh * 16) ^ sw2;
            bf16x8 a[4];
            #pragma unroll
            for (int mt = 0; mt < 4; ++mt)
                a[mt] = *(const bf16x8*)((const char*)cbuf + (mt * 16 + lm) * 128 + kb);
            #pragma unroll
            for (int mt = 0; mt < 4; ++mt)
                #pragma unroll
                for (int nt = 0; nt < 3; ++nt)
                    acc[mt][nt] = __builtin_amdgcn_mfma_f32_16x16x32_bf16(
                        a[mt], bbA[nt], acc[mt][nt], 0, 0, 0);
        }
        // ---- kk = 1: prefetch bbA (next kt's kk=0), compute with bbB ----
        {
            if (kt < 11) {
                #pragma unroll
                for (int nt = 0; nt < 3; ++nt)
                    bbA[nt] = *(const bf16x8*)(gW2w + (size_t)nt * 16 * 768 + (kt + 1) * 64);
            }
            int kb = (64 + kh * 16) ^ sw2;
            bf16x8 a[4];
            #pragma unroll
            for (int mt = 0; mt < 4; ++mt)
                a[mt] = *(const bf16x8*)((const char*)cbuf + (mt * 16 + lm) * 128 + kb);
            #pragma unroll
            for (int mt = 0; mt < 4; ++mt)
                #pragma unroll
                for (int nt = 0; nt < 3; ++nt)
                    acc[mt][nt] = __builtin_amdgcn_mfma_f32_16x16x32_bf16(
                        a[mt], bbB[nt], acc[mt][nt], 0, 0, 0);
        }
        // write-late: gelu + LDS store for kt+1
        if (kt < 11) {
            u128 o;
            #pragma unroll
            for (int i = 0; i < 8; ++i)
                o.u[i] = f2bf(gelu_fast(bf2f(xn.u[i]) + U.p.sXseg[(kt + 1) * 64 + ci * 8 + i]));
            *(uint4*)((char*)nbuf + ar * 128 + ((ci * 16) ^ asw)) = o.v;
        }
    }

    // epilogue: h3[row] = sum_n gelu(h2+b2[n])*W3[n]; sigmoid; masked max
    float b2v[3], w3v[3];
    #pragma unroll
    for (int nt = 0; nt < 3; ++nt) {
        int n = w * 48 + nt * 16 + lm;
        b2v[nt] = b2[n]; w3v[nt] = W3[n];
    }
    #pragma unroll
    for (int mt = 0; mt < 4; ++mt) {
        #pragma unroll
        for (int j = 0; j < 4; ++j) {
            float s = 0.f;
            #pragma unroll
            for (int nt = 0; nt < 3; ++nt)
                s += gelu_fast(acc[mt][nt][j] + b2v[nt]) * w3v[nt];
            s += __shfl_xor(s, 1); s += __shfl_xor(s, 2);
            s += __shfl_xor(s, 4); s += __shfl_xor(s, 8);
            if (lm == 0) U.p.sRed[mt * 16 + kh * 4 + j][w] = s;
        }
    }
    __syncthreads();
    if (w == 0) {
        float h3 = U.p.sRed[l][0] + U.p.sRed[l][1] + U.p.sRed[l][2] + U.p.sRed[l][3]
                 + U.p.sRed[l][4] + U.p.sRed[l][5] + U.p.sRed[l][6] + U.p.sRed[l][7]
                 + b3v;
        float sig = sigmoid_fast(h3);
        float val = (l < ndb) ? sig : 0.f;
        #pragma unroll
        for (int off = 32; off > 0; off >>= 1) val = fmaxf(val, __shfl_xor(val, off));
        if (l == 0) {
            float pv = segscale * val;
            out_pred[bs] = pv;
            predv[bs] = pv;
        }
    }
}

// ---------------------------------------------------------------------------
// k_final (unchanged, verified round 8)
// ---------------------------------------------------------------------------
__global__ __launch_bounds__(256) void k_final(
    const int* __restrict__ ns, const float* __restrict__ dcws,
    const float* __restrict__ Rws, const float* __restrict__ predv,
    float* __restrict__ out)
{
    __shared__ float sl1[32], sl2[32];
    int t = threadIdx.x;
    if (t < 32) {
        int nsb = ns[t];
        float sb = 0.f;
        #pragma unroll
        for (int s = 0; s < 16; ++s) {
            float d = fabsf(dcws[t * 16 + s] - predv[t * 16 + s]);
            sb += (s < nsb) ? d : 0.f;
        }
        sl1[t] = sb / (float)nsb;
    }
    {
        int b = t >> 3, c = t & 7;
        int nsb = ns[b];
        float sum = 0.f;
        #pragma unroll
        for (int k = 0; k < 32; ++k) {
            int idx = c * 32 + k;
            int s = idx >> 4, tt = idx & 15;
            float R = Rws[b * 256 + idx];
            float ps = predv[b * 16 + s], pt = predv[b * 16 + tt];
            float t1 = (1.f - ps) * (1.f - pt), t2 = ps * pt;
            float term = fabsf(t1 - R) * fabsf(t2 - R);
            sum += (s < nsb && tt < nsb) ? term : 0.f;
        }
        sum += __shfl_xor(sum, 1);
        sum += __shfl_xor(sum, 2);
        sum += __shfl_xor(sum, 4);
        if (c == 0) sl2[b] = sum / (float)nsb;
    }
    __syncthreads();
    if (t == 0) {
        float a = 0.f, bsum = 0.f;
        #pragma unroll
        for (int i = 0; i < 32; ++i) { a += sl1[i]; bsum += sl2[i]; }
        out[1088] = a * (1.0f / 32.0f);
        out[1089] = bsum * (1.0f / 32.0f);
    }
}

// ---------------------------------------------------------------------------
extern "C" void kernel_launch(void* const* d_in, const int* in_sizes, int n_in,
                              void* d_out, int out_size, void* d_ws, size_t ws_size,
                              hipStream_t stream)
{
    const float* doc  = (const float*)d_in[0];
    const float* seg  = (const float*)d_in[1];
    const int*   nd   = (const int*)d_in[2];
    const int*   ns   = (const int*)d_in[3];
    const float* tagg = (const float*)d_in[4];
    const float* tis  = (const float*)d_in[5];
    const float* W1   = (const float*)d_in[6];   // [1536][768]
    const float* b1   = (const float*)d_in[7];
    const float* W2   = (const float*)d_in[8];   // [768][384]
    const float* b2   = (const float*)d_in[9];
    const float* W3   = (const float*)d_in[10];
    const float* b3   = (const float*)d_in[11];
    float* out = (float*)d_out;

    float* fws      = (float*)d_ws;
    float* dscale   = fws;                 // 2048
    float* sscale   = dscale + 2048;       // 512
    float* smean    = sscale + 512;        // 512
    float* cscale   = smean + 512;         // 512
    float* predv    = cscale + 512;        // 512
    float* dcws     = predv + 512;         // 512
    float* Rws      = dcws + 512;          // 8192
    unsigned short* docB  = (unsigned short*)(Rws + 8192);
    unsigned short* segB  = docB + (size_t)2048 * 768;
    unsigned short* W1T   = segB + (size_t)512 * 768;     // [768][1536]
    unsigned short* W2T   = W1T + (size_t)768 * 1536;     // [384][768]
    unsigned short* XdocB = W2T + (size_t)384 * 768;      // [2048][768]
    unsigned short* XsegB = XdocB + (size_t)2048 * 768;   // [512][768]

    k_prep<<<1001, 256, 0, stream>>>(doc, seg, W1, W2, tagg, tis, ns,
                                     dscale, sscale, smean, cscale,
                                     docB, segB, W1T, W2T, out);
    k_l1<<<dim3(40, 6), 256, 0, stream>>>(docB, segB, W1T, b1, XdocB, XsegB);
    k_fused_mfma<<<576, 512, 0, stream>>>(XdocB, XsegB, W2T, b2, W3, b3, nd, ns,
                                          docB, segB, seg, dscale, sscale,
                                          smean, cscale, out + 544, predv,
                                          dcws, Rws);
    k_final<<<1, 256, 0, stream>>>(ns, dcws, Rws, predv, out);
}

// Round 12
// 82.518 us; speedup vs baseline: 1.3885x; 1.0627x over previous
//
#include <hip/hip_runtime.h>
#include <hip/hip_bf16.h>
#include <math.h>

// Problem constants: B=32, S=16, D=64, E=768
#define EPSF 1e-12f

typedef short bf16x8 __attribute__((ext_vector_type(8)));
typedef float f32x4  __attribute__((ext_vector_type(4)));

__device__ __forceinline__ float gelu_fast(float x) {
    float x2 = x * x;
    float z = -2.3021184f * x * fmaf(0.044715f, x2, 1.0f);
    float u = __builtin_amdgcn_exp2f(z);
    return x * __builtin_amdgcn_rcpf(1.0f + u);
}
__device__ __forceinline__ float sigmoid_fast(float x) {
    float u = __builtin_amdgcn_exp2f(-1.44269504f * x);
    return __builtin_amdgcn_rcpf(1.0f + u);
}
__device__ __forceinline__ float bf2f(unsigned short u) {
    return __uint_as_float(((unsigned int)u) << 16);
}
__device__ __forceinline__ unsigned short f2bf(float f) {
    unsigned int u = __float_as_uint(f);
    u += 0x7FFFu + ((u >> 16) & 1u);     // RNE
    return (unsigned short)(u >> 16);
}

// ---------------------------------------------------------------------------
// k_prep: [0,640) norms+bf16-cvt (float4-vectorized); [640,1000) W1/W2
// transpose; 1000: passthrough copies.
// ---------------------------------------------------------------------------
__global__ __launch_bounds__(256) void k_prep(
    const float* __restrict__ doc, const float* __restrict__ seg,
    const float* __restrict__ W1, const float* __restrict__ W2,
    const float* __restrict__ tagg, const float* __restrict__ tis,
    const int* __restrict__ ns,
    float* __restrict__ dscale, float* __restrict__ sscale,
    float* __restrict__ smean, float* __restrict__ cscale,
    unsigned short* __restrict__ docB, unsigned short* __restrict__ segB,
    unsigned short* __restrict__ W1T, unsigned short* __restrict__ W2T,
    float* __restrict__ out)
{
    __shared__ float sT[64][65];
    int blk = blockIdx.x;
    int t = threadIdx.x;
    if (blk == 1000) {
        if (t < 32) out[t] = tagg[t];
        out[32 + t] = tis[t];
        out[32 + 256 + t] = tis[256 + t];
        if (t < 32) out[1056 + t] = (float)ns[t];
        return;
    }
    if (blk < 640) {
        int row = blk * 4 + (t >> 6);
        int lane = t & 63;
        const float* src = (row < 2048) ? (doc + (size_t)row * 768)
                                        : (seg + (size_t)(row - 2048) * 768);
        unsigned short* dst = (row < 2048) ? (docB + (size_t)row * 768)
                                           : (segB + (size_t)(row - 2048) * 768);
        float ss = 0.f, sm = 0.f;
        float4 v0 = *(const float4*)(src + lane * 4);
        float4 v1 = *(const float4*)(src + lane * 4 + 256);
        float4 v2 = *(const float4*)(src + lane * 4 + 512);
        ss += v0.x * v0.x + v0.y * v0.y + v0.z * v0.z + v0.w * v0.w;
        ss += v1.x * v1.x + v1.y * v1.y + v1.z * v1.z + v1.w * v1.w;
        ss += v2.x * v2.x + v2.y * v2.y + v2.z * v2.z + v2.w * v2.w;
        sm += v0.x + v0.y + v0.z + v0.w;
        sm += v1.x + v1.y + v1.z + v1.w;
        sm += v2.x + v2.y + v2.z + v2.w;
        {
            ushort4 o;
            o.x = f2bf(v0.x); o.y = f2bf(v0.y); o.z = f2bf(v0.z); o.w = f2bf(v0.w);
            *(ushort4*)(dst + lane * 4) = o;
            o.x = f2bf(v1.x); o.y = f2bf(v1.y); o.z = f2bf(v1.z); o.w = f2bf(v1.w);
            *(ushort4*)(dst + lane * 4 + 256) = o;
            o.x = f2bf(v2.x); o.y = f2bf(v2.y); o.z = f2bf(v2.z); o.w = f2bf(v2.w);
            *(ushort4*)(dst + lane * 4 + 512) = o;
        }
        #pragma unroll
        for (int off = 32; off > 0; off >>= 1) {
            ss += __shfl_down(ss, off);
            sm += __shfl_down(sm, off);
        }
        if (lane == 0) {
            if (row < 2048) {
                dscale[row] = rsqrtf(fmaxf(ss, EPSF));
            } else {
                int r = row - 2048;
                sscale[r] = rsqrtf(fmaxf(ss, EPSF));
                float mean = sm * (1.0f / 768.0f);
                smean[r] = mean;
                cscale[r] = rsqrtf(fmaxf(ss - sm * mean, EPSF));
            }
        }
        return;
    }
    int tt = blk - 640;
    const float* in; unsigned short* out2; int R, C, bx, by;
    if (tt < 288) { in = W1; out2 = W1T; R = 1536; C = 768; bx = tt % 12; by = tt / 12; }
    else { tt -= 288; in = W2; out2 = W2T; R = 768; C = 384; bx = tt % 6; by = tt / 6; }
    int c0 = bx * 64, r0 = by * 64;
    int tr = t >> 2, tc4 = (t & 3) * 16;
    #pragma unroll
    for (int i = 0; i < 4; ++i) {
        float4 v = *(const float4*)(in + (size_t)(r0 + tr) * C + c0 + tc4 + i * 4);
        sT[tr][tc4 + i * 4 + 0] = v.x; sT[tr][tc4 + i * 4 + 1] = v.y;
        sT[tr][tc4 + i * 4 + 2] = v.z; sT[tr][tc4 + i * 4 + 3] = v.w;
    }
    __syncthreads();
    union { uint4 v; unsigned short u[8]; } o0, o1;
    #pragma unroll
    for (int i = 0; i < 8; ++i) o0.u[i] = f2bf(sT[tc4 + i][tr]);
    #pragma unroll
    for (int i = 0; i < 8; ++i) o1.u[i] = f2bf(sT[tc4 + 8 + i][tr]);
    *(uint4*)(out2 + (size_t)(c0 + tr) * R + r0 + tc4) = o0.v;
    *(uint4*)(out2 + (size_t)(c0 + tr) * R + r0 + tc4 + 8) = o1.v;
}

// ---------------------------------------------------------------------------
// Layer-1 MFMA GEMM: full-kt-deep register prefetch. Grid-limited occupancy
// (240 blocks = 1/CU), so the +48 VGPR for 24 fragment buffers is free;
// prefetch distance ~1 kt (~400cyc) covers L2 latency at 1 wave/SIMD.
// ---------------------------------------------------------------------------
__global__ __launch_bounds__(256) void k_l1(
    const unsigned short* __restrict__ docB, const unsigned short* __restrict__ segB,
    const unsigned short* __restrict__ W1T_bf, const float* __restrict__ b1,
    unsigned short* __restrict__ XdocB, unsigned short* __restrict__ XsegB)
{
    int mb = blockIdx.x;
    int n0 = blockIdx.y * 128;
    int t = threadIdx.x, w = t >> 6, l = t & 63;
    int lm = l & 15, kh = l >> 4;
    bool isdoc = (mb < 32);
    int m0 = isdoc ? mb * 64 : (mb - 32) * 64;
    const unsigned short* A = isdoc ? docB : segB;
    int koff = isdoc ? 0 : 768;
    unsigned short* C = isdoc ? XdocB : XsegB;

    const unsigned short* gA = A + (size_t)(m0 + lm) * 768 + kh * 8;
    const unsigned short* gB = W1T_bf + (size_t)(n0 + w * 32 + lm) * 1536 + koff + kh * 8;

    f32x4 acc[4][2];
    #pragma unroll
    for (int mt = 0; mt < 4; ++mt)
        #pragma unroll
        for (int nt = 0; nt < 2; ++nt) acc[mt][nt] = (f32x4){0.f, 0.f, 0.f, 0.f};

    // Two named full-kt fragment sets (8 A + 4 B each).
    bf16x8 a0A[4], a1A[4], b0A[2], b1A[2];
    bf16x8 a0B[4], a1B[4], b0B[2], b1B[2];
    #pragma unroll
    for (int mt = 0; mt < 4; ++mt) {
        a0A[mt] = *(const bf16x8*)(gA + (size_t)mt * 16 * 768);
        a1A[mt] = *(const bf16x8*)(gA + (size_t)mt * 16 * 768 + 32);
    }
    #pragma unroll
    for (int nt = 0; nt < 2; ++nt) {
        b0A[nt] = *(const bf16x8*)(gB + (size_t)nt * 16 * 1536);
        b1A[nt] = *(const bf16x8*)(gB + (size_t)nt * 16 * 1536 + 32);
    }

    #define L1_BODY(KT, A0, A1, B0, B1, NA0, NA1, NB0, NB1)                     \
    {                                                                           \
        if ((KT) < 11) {                                                        \
            int ko = ((KT) + 1) * 64;                                           \
            _Pragma("unroll")                                                   \
            for (int mt = 0; mt < 4; ++mt) {                                    \
                NA0[mt] = *(const bf16x8*)(gA + (size_t)mt * 16 * 768 + ko);    \
                NA1[mt] = *(const bf16x8*)(gA + (size_t)mt * 16 * 768 + ko + 32); \
            }                                                                   \
            _Pragma("unroll")                                                   \
            for (int nt = 0; nt < 2; ++nt) {                                    \
                NB0[nt] = *(const bf16x8*)(gB + (size_t)nt * 16 * 1536 + ko);   \
                NB1[nt] = *(const bf16x8*)(gB + (size_t)nt * 16 * 1536 + ko + 32); \
            }                                                                   \
        }                                                                       \
        _Pragma("unroll")                                                       \
        for (int mt = 0; mt < 4; ++mt)                                          \
            _Pragma("unroll")                                                   \
            for (int nt = 0; nt < 2; ++nt)                                      \
                acc[mt][nt] = __builtin_amdgcn_mfma_f32_16x16x32_bf16(          \
                    A0[mt], B0[nt], acc[mt][nt], 0, 0, 0);                      \
        _Pragma("unroll")                                                       \
        for (int mt = 0; mt < 4; ++mt)                                          \
            _Pragma("unroll")                                                   \
            for (int nt = 0; nt < 2; ++nt)                                      \
                acc[mt][nt] = __builtin_amdgcn_mfma_f32_16x16x32_bf16(          \
                    A1[mt], B1[nt], acc[mt][nt], 0, 0, 0);                      \
    }

    for (int kt2 = 0; kt2 < 12; kt2 += 2) {
        L1_BODY(kt2,     a0A, a1A, b0A, b1A, a0B, a1B, b0B, b1B);
        L1_BODY(kt2 + 1, a0B, a1B, b0B, b1B, a0A, a1A, b0A, b1A);
    }
    #undef L1_BODY

    #pragma unroll
    for (int nt = 0; nt < 2; ++nt) {
        int n = n0 + w * 32 + nt * 16 + lm;
        float bv = isdoc ? 0.f : b1[n];
        #pragma unroll
        for (int mt = 0; mt < 4; ++mt)
            #pragma unroll
            for (int j = 0; j < 4; ++j) {
                int row = m0 + mt * 16 + kh * 4 + j;
                C[(size_t)row * 768 + n] = f2bf(acc[mt][nt][j] + bv);
            }
    }
}

// ---------------------------------------------------------------------------
// Fused layer-2+3 MFMA (round-8 verified body) + s_setprio around MFMA
// clusters. blocks [0,512): pred; [512,544): cos rider; [544,576): corr rider.
// ---------------------------------------------------------------------------
__global__ __launch_bounds__(256, 2) void k_fused_mfma(
    const unsigned short* __restrict__ XdocB, const unsigned short* __restrict__ XsegB,
    const unsigned short* __restrict__ W2T_bf,
    const float* __restrict__ b2, const float* __restrict__ W3, const float* __restrict__ b3,
    const int* __restrict__ nd, const int* __restrict__ ns,
    const unsigned short* __restrict__ docB, const unsigned short* __restrict__ segB,
    const float* __restrict__ seg,
    const float* __restrict__ dscale, const float* __restrict__ sscale,
    const float* __restrict__ smean, const float* __restrict__ cscale,
    float* __restrict__ out_pred, float* __restrict__ predv,
    float* __restrict__ dcws, float* __restrict__ Rws)
{
    __shared__ union {
        struct {
            unsigned short sA0[64 * 64];   // 8KB, swizzled rows of 128B
            unsigned short sA1[64 * 64];   // 8KB
            float sXseg[768];              // 3KB
            float sRed[64][4];             // 1KB
        } p;
        struct { float sRedC[16][4]; } c;
        struct { unsigned short zb[16][776]; } r;   // ~24.8KB
    } U;

    int blk = blockIdx.x;
    int t = threadIdx.x, w = t >> 6, l = t & 63;
    int lm = l & 15, kh = l >> 4;

    if (blk >= 512) {
        if (blk < 544) {
            // ---- cos rider ----
            int b = blk - 512;
            const unsigned short* gS = segB + (size_t)(b * 16 + lm) * 768 + kh * 8;
            const unsigned short* gD = docB + (size_t)(b * 64 + w * 16 + lm) * 768 + kh * 8;
            f32x4 acc = (f32x4){0.f, 0.f, 0.f, 0.f};
            for (int kt = 0; kt < 24; ++kt) {
                bf16x8 a = *(const bf16x8*)(gS + kt * 32);
                bf16x8 bb = *(const bf16x8*)(gD + kt * 32);
                acc = __builtin_amdgcn_mfma_f32_16x16x32_bf16(a, bb, acc, 0, 0, 0);
            }
            int ndb = nd[b];
            int d = w * 16 + lm;
            float dsc = dscale[b * 64 + d];
            #pragma unroll
            for (int j = 0; j < 4; ++j) {
                int s = kh * 4 + j;
                float cosv = acc[j] * sscale[b * 16 + s] * dsc;
                float sim = (d < ndb) ? (1.0f - cosv) * 0.5f : 0.f;
                sim = fmaxf(sim, __shfl_xor(sim, 1));
                sim = fmaxf(sim, __shfl_xor(sim, 2));
                sim = fmaxf(sim, __shfl_xor(sim, 4));
                sim = fmaxf(sim, __shfl_xor(sim, 8));
                if (lm == 0) U.c.sRedC[s][w] = sim;
            }
            __syncthreads();
            if (t < 16) {
                float dc = fmaxf(fmaxf(U.c.sRedC[t][0], U.c.sRedC[t][1]),
                                 fmaxf(U.c.sRedC[t][2], U.c.sRedC[t][3]));
                dcws[b * 16 + t] = dc;
            }
        } else {
            // ---- corr rider ----
            int b = blk - 544;
            for (int i = t; i < 16 * 768; i += 256) {
                int s = i / 768; int e = i - s * 768;
                U.r.zb[s][e] = f2bf((seg[((size_t)b * 16 + s) * 768 + e]
                                     - smean[b * 16 + s]) * cscale[b * 16 + s]);
            }
            __syncthreads();
            if (w == 0) {
                f32x4 acc = (f32x4){0.f, 0.f, 0.f, 0.f};
                #pragma unroll
                for (int kt = 0; kt < 24; ++kt) {
                    bf16x8 z = *(const bf16x8*)&U.r.zb[lm][kt * 32 + kh * 8];
                    acc = __builtin_amdgcn_mfma_f32_16x16x32_bf16(z, z, acc, 0, 0, 0);
                }
                #pragma unroll
                for (int j = 0; j < 4; ++j) {
                    int row = kh * 4 + j;
                    Rws[b * 256 + row * 16 + lm] = 0.5f * (1.0f + acc[j]);
                }
            }
        }
        return;
    }

    // ---------------- pred path (round-8 verified + setprio) ----------------
    int bs = blk;
    int b = bs >> 4;
    int sw2 = (lm & 7) << 4;

    for (int i = t; i < 768; i += 256) U.p.sXseg[i] = bf2f(XsegB[(size_t)bs * 768 + i]);

    const int ndb = nd[b];
    const float segscale = (ns[b] > 10) ? 1.0f : 100.0f;
    const float b3v = b3[0];

    f32x4 acc[4][6];
    #pragma unroll
    for (int mt = 0; mt < 4; ++mt)
        #pragma unroll
        for (int nt = 0; nt < 6; ++nt) acc[mt][nt] = (f32x4){0.f, 0.f, 0.f, 0.f};

    int ar = t >> 2, ak = (t & 3) * 16;
    int asw = (ar & 7) << 4;
    const char* gXd = (const char*)XdocB + (size_t)(b * 64 + ar) * 1536;
    const unsigned short* gW2w = W2T_bf + (size_t)(w * 96 + lm) * 768 + kh * 8;

    union u128 { uint4 v; unsigned short u[8]; };

    bf16x8 bbA[6], bbB[6];
    #pragma unroll
    for (int nt = 0; nt < 6; ++nt)
        bbA[nt] = *(const bf16x8*)(gW2w + (size_t)nt * 16 * 768);

    {
        u128 xc0, xc1;
        xc0.v = *(const uint4*)(gXd + ak * 2);
        xc1.v = *(const uint4*)(gXd + ak * 2 + 16);
        __syncthreads();          // sXseg ready
        u128 o0, o1;
        #pragma unroll
        for (int i = 0; i < 8; ++i)
            o0.u[i] = f2bf(gelu_fast(bf2f(xc0.u[i]) + U.p.sXseg[ak + i]));
        #pragma unroll
        for (int i = 0; i < 8; ++i)
            o1.u[i] = f2bf(gelu_fast(bf2f(xc1.u[i]) + U.p.sXseg[ak + 8 + i]));
        *(uint4*)((char*)U.p.sA0 + ar * 128 + ((ak * 2) ^ asw)) = o0.v;
        *(uint4*)((char*)U.p.sA0 + ar * 128 + ((ak * 2 + 16) ^ asw)) = o1.v;
    }

    #pragma unroll
    for (int kt = 0; kt < 12; ++kt) {
        unsigned short* cbuf = (kt & 1) ? U.p.sA1 : U.p.sA0;
        unsigned short* nbuf = (kt & 1) ? U.p.sA0 : U.p.sA1;
        __syncthreads();
        u128 xn0, xn1;
        if (kt < 11) {
            xn0.v = *(const uint4*)(gXd + (kt + 1) * 128 + ak * 2);
            xn1.v = *(const uint4*)(gXd + (kt + 1) * 128 + ak * 2 + 16);
        }
        // ---- kk = 0 ----
        {
            #pragma unroll
            for (int nt = 0; nt < 6; ++nt)
                bbB[nt] = *(const bf16x8*)(gW2w + (size_t)nt * 16 * 768 + kt * 64 + 32);
            int kb = (kh * 16) ^ sw2;
            bf16x8 a[4];
            #pragma unroll
            for (int mt = 0; mt < 4; ++mt)
                a[mt] = *(const bf16x8*)((const char*)cbuf + (mt * 16 + lm) * 128 + kb);
            __builtin_amdgcn_s_setprio(1);
            #pragma unroll
            for (int mt = 0; mt < 4; ++mt)
                #pragma unroll
                for (int nt = 0; nt < 6; ++nt)
                    acc[mt][nt] = __builtin_amdgcn_mfma_f32_16x16x32_bf16(
                        a[mt], bbA[nt], acc[mt][nt], 0, 0, 0);
            __builtin_amdgcn_s_setprio(0);
        }
        // ---- kk = 1 ----
        {
            if (kt < 11) {
                #pragma unroll
                for (int nt = 0; nt < 6; ++nt)
                    bbA[nt] = *(const bf16x8*)(gW2w + (size_t)nt * 16 * 768 + (kt + 1) * 64);
            }
            int kb = (64 + kh * 16) ^ sw2;
            bf16x8 a[4];
            #pragma unroll
            for (int mt = 0; mt < 4; ++mt)
                a[mt] = *(const bf16x8*)((const char*)cbuf + (mt * 16 + lm) * 128 + kb);
            __builtin_amdgcn_s_setprio(1);
            #pragma unroll
            for (int mt = 0; mt < 4; ++mt)
                #pragma unroll
                for (int nt = 0; nt < 6; ++nt)
                    acc[mt][nt] = __builtin_amdgcn_mfma_f32_16x16x32_bf16(
                        a[mt], bbB[nt], acc[mt][nt], 0, 0, 0);
            __builtin_amdgcn_s_setprio(0);
        }
        // write-late
        if (kt < 11) {
            u128 o0, o1;
            #pragma unroll
            for (int i = 0; i < 8; ++i)
                o0.u[i] = f2bf(gelu_fast(bf2f(xn0.u[i]) + U.p.sXseg[(kt + 1) * 64 + ak + i]));
            #pragma unroll
            for (int i = 0; i < 8; ++i)
                o1.u[i] = f2bf(gelu_fast(bf2f(xn1.u[i]) + U.p.sXseg[(kt + 1) * 64 + ak + 8 + i]));
            *(uint4*)((char*)nbuf + ar * 128 + ((ak * 2) ^ asw)) = o0.v;
            *(uint4*)((char*)nbuf + ar * 128 + ((ak * 2 + 16) ^ asw)) = o1.v;
        }
    }

    // epilogue
    float b2v[6], w3v[6];
    #pragma unroll
    for (int nt = 0; nt < 6; ++nt) {
        int n = w * 96 + nt * 16 + lm;
        b2v[nt] = b2[n]; w3v[nt] = W3[n];
    }
    #pragma unroll
    for (int mt = 0; mt < 4; ++mt) {
        #pragma unroll
        for (int j = 0; j < 4; ++j) {
            float s = 0.f;
            #pragma unroll
            for (int nt = 0; nt < 6; ++nt)
                s += gelu_fast(acc[mt][nt][j] + b2v[nt]) * w3v[nt];
            s += __shfl_xor(s, 1); s += __shfl_xor(s, 2);
            s += __shfl_xor(s, 4); s += __shfl_xor(s, 8);
            if (lm == 0) U.p.sRed[mt * 16 + kh * 4 + j][w] = s;
        }
    }
    __syncthreads();
    if (w == 0) {
        float h3 = U.p.sRed[l][0] + U.p.sRed[l][1] + U.p.sRed[l][2] + U.p.sRed[l][3] + b3v;
        float sig = sigmoid_fast(h3);
        float val = (l < ndb) ? sig : 0.f;
        #pragma unroll
        for (int off = 32; off > 0; off >>= 1) val = fmaxf(val, __shfl_xor(val, off));
        if (l == 0) {
            float pv = segscale * val;
            out_pred[bs] = pv;
            predv[bs] = pv;
        }
    }
}

// ---------------------------------------------------------------------------
// k_final (round-8 verified)
// ---------------------------------------------------------------------------
__global__ __launch_bounds__(256) void k_final(
    const int* __restrict__ ns, const float* __restrict__ dcws,
    const float* __restrict__ Rws, const float* __restrict__ predv,
    float* __restrict__ out)
{
    __shared__ float sl1[32], sl2[32];
    int t = threadIdx.x;
    if (t < 32) {
        int nsb = ns[t];
        float sb = 0.f;
        #pragma unroll
        for (int s = 0; s < 16; ++s) {
            float d = fabsf(dcws[t * 16 + s] - predv[t * 16 + s]);
            sb += (s < nsb) ? d : 0.f;
        }
        sl1[t] = sb / (float)nsb;
    }
    {
        int b = t >> 3, c = t & 7;
        int nsb = ns[b];
        float sum = 0.f;
        #pragma unroll
        for (int k = 0; k < 32; ++k) {
            int idx = c * 32 + k;
            int s = idx >> 4, tt = idx & 15;
            float R = Rws[b * 256 + idx];
            float ps = predv[b * 16 + s], pt = predv[b * 16 + tt];
            float t1 = (1.f - ps) * (1.f - pt), t2 = ps * pt;
            float term = fabsf(t1 - R) * fabsf(t2 - R);
            sum += (s < nsb && tt < nsb) ? term : 0.f;
        }
        sum += __shfl_xor(sum, 1);
        sum += __shfl_xor(sum, 2);
        sum += __shfl_xor(sum, 4);
        if (c == 0) sl2[b] = sum / (float)nsb;
    }
    __syncthreads();
    if (t == 0) {
        float a = 0.f, bsum = 0.f;
        #pragma unroll
        for (int i = 0; i < 32; ++i) { a += sl1[i]; bsum += sl2[i]; }
        out[1088] = a * (1.0f / 32.0f);
        out[1089] = bsum * (1.0f / 32.0f);
    }
}

// ---------------------------------------------------------------------------
extern "C" void kernel_launch(void* const* d_in, const int* in_sizes, int n_in,
                              void* d_out, int out_size, void* d_ws, size_t ws_size,
                              hipStream_t stream)
{
    const float* doc  = (const float*)d_in[0];
    const float* seg  = (const float*)d_in[1];
    const int*   nd   = (const int*)d_in[2];
    const int*   ns   = (const int*)d_in[3];
    const float* tagg = (const float*)d_in[4];
    const float* tis  = (const float*)d_in[5];
    const float* W1   = (const float*)d_in[6];   // [1536][768]
    const float* b1   = (const float*)d_in[7];
    const float* W2   = (const float*)d_in[8];   // [768][384]
    const float* b2   = (const float*)d_in[9];
    const float* W3   = (const float*)d_in[10];
    const float* b3   = (const float*)d_in[11];
    float* out = (float*)d_out;

    float* fws      = (float*)d_ws;
    float* dscale   = fws;                 // 2048
    float* sscale   = dscale + 2048;       // 512
    float* smean    = sscale + 512;        // 512
    float* cscale   = smean + 512;         // 512
    float* predv    = cscale + 512;        // 512
    float* dcws     = predv + 512;         // 512
    float* Rws      = dcws + 512;          // 8192
    unsigned short* docB  = (unsigned short*)(Rws + 8192);
    unsigned short* segB  = docB + (size_t)2048 * 768;
    unsigned short* W1T   = segB + (size_t)512 * 768;     // [768][1536]
    unsigned short* W2T   = W1T + (size_t)768 * 1536;     // [384][768]
    unsigned short* XdocB = W2T + (size_t)384 * 768;      // [2048][768]
    unsigned short* XsegB = XdocB + (size_t)2048 * 768;   // [512][768]

    k_prep<<<1001, 256, 0, stream>>>(doc, seg, W1, W2, tagg, tis, ns,
                                     dscale, sscale, smean, cscale,
                                     docB, segB, W1T, W2T, out);
    k_l1<<<dim3(40, 6), 256, 0, stream>>>(docB, segB, W1T, b1, XdocB, XsegB);
    k_fused_mfma<<<576, 256, 0, stream>>>(XdocB, XsegB, W2T, b2, W3, b3, nd, ns,
                                          docB, segB, seg, dscale, sscale,
                                          smean, cscale, out + 544, predv,
                                          dcws, Rws);
    k_final<<<1, 256, 0, stream>>>(ns, dcws, Rws, predv, out);
}